// Round 1
// baseline (1162.623 us; speedup 1.0000x reference)
//
#include <hip/hip_runtime.h>
#include <hip/hip_bf16.h>

#define N_NODES 50000
#define N_EDGES 800000
#define N_GRAPHS 64

// ---------------------------------------------------------------------------
// Edge kernel: one wave per edge. Per lane: FPL features, lew column(s) in
// VGPRs. edge_attr row is wave-uniform -> scalar loads -> pure v_fma inner
// loop with SGPR broadcast operand. Scatter via native fp32 atomics.
// ---------------------------------------------------------------------------
template <int DIN>
__global__ __launch_bounds__(256) void edge_kernel(
    const float* __restrict__ x, const float* __restrict__ ea,
    const int* __restrict__ ei, const float* __restrict__ lew,
    const float* __restrict__ leb, float* __restrict__ agg, int E) {
  constexpr int FPL = DIN / 64;  // features per lane
  const int lane = threadIdx.x & 63;
  const int wave = __builtin_amdgcn_readfirstlane(threadIdx.x >> 6);
  const int wid = blockIdx.x * (256 >> 6) + wave;
  const int nw = gridDim.x * (256 >> 6);

  float w[32][FPL];
  float bb[FPL];
#pragma unroll
  for (int p = 0; p < FPL; ++p) bb[p] = leb[lane + 64 * p];
#pragma unroll
  for (int k = 0; k < 32; ++k)
#pragma unroll
    for (int p = 0; p < FPL; ++p) w[k][p] = lew[k * DIN + lane + 64 * p];

  const int* __restrict__ srcp = ei;
  const int* __restrict__ dstp = ei + E;

  for (int j = wid; j < E; j += nw) {
    float acc[FPL];
#pragma unroll
    for (int p = 0; p < FPL; ++p) acc[p] = bb[p];
    const float* __restrict__ earow = ea + (size_t)j * 32;
#pragma unroll
    for (int k = 0; k < 32; ++k) {
      float eak = earow[k];  // wave-uniform -> s_load, SGPR operand
#pragma unroll
      for (int p = 0; p < FPL; ++p) acc[p] = fmaf(eak, w[k][p], acc[p]);
    }
    const int s = srcp[j];
    const int d = dstp[j];
#pragma unroll
    for (int p = 0; p < FPL; ++p) {
      float m = x[(size_t)s * DIN + lane + 64 * p] + acc[p];
      m = m > 0.f ? m : 0.f;
      unsafeAtomicAdd(&agg[(size_t)d * DIN + lane + 64 * p], m);
    }
  }
}

// ---------------------------------------------------------------------------
// Node GEMM: out[n,f] = relu((in[n,:] (+add[n,:])) @ w + bias), optional
// eval-mode BN folded in before the relu. 8 nodes per block, 4 outputs per
// thread (float4), weights staged in LDS.
// blockDim = (M/4)*8.
// ---------------------------------------------------------------------------
template <int K, int M, bool FUSE_ADD, bool DO_BN>
__global__ void mlp_gemm(const float* __restrict__ in,
                         const float* __restrict__ add,
                         const float* __restrict__ w,
                         const float* __restrict__ bias,
                         const float* __restrict__ bng,
                         const float* __restrict__ bnb,
                         const float* __restrict__ bnm,
                         const float* __restrict__ bnv,
                         float* __restrict__ out, int N) {
  constexpr int Q = M / 4;    // threads per node
  constexpr int NPB = 8;      // nodes per block
  __shared__ alignas(16) float ws_[K * M];
  __shared__ alignas(16) float hin[NPB * K];
  __shared__ alignas(16) float bnA[DO_BN ? M : 4];
  __shared__ alignas(16) float bnB[DO_BN ? M : 4];

  const int tid = threadIdx.x;
  const int bdim = Q * NPB;

  for (int i = tid; i < K * M / 4; i += bdim)
    ((float4*)ws_)[i] = ((const float4*)w)[i];
  if constexpr (DO_BN) {
    for (int f = tid; f < M; f += bdim) {
      float s = bng[f] * rsqrtf(bnv[f] + 1e-5f);
      bnA[f] = s;
      bnB[f] = bnb[f] - bnm[f] * s;
    }
  }
  const int nb = blockIdx.x * NPB;
  for (int i = tid; i < NPB * K; i += bdim) {
    const int dn = i / K;
    const int col = i - dn * K;
    const int n = nb + dn;
    float v = 0.f;
    if (n < N) {
      v = in[(size_t)n * K + col];
      if constexpr (FUSE_ADD) v += add[(size_t)n * K + col];
    }
    hin[i] = v;
  }
  __syncthreads();

  const int ns = tid / Q;
  const int q = tid - ns * Q;
  const int n = nb + ns;

  float4 acc = ((const float4*)bias)[q];
#pragma unroll 8
  for (int k = 0; k < K; ++k) {
    const float hv = hin[ns * K + k];
    const float4 wv = ((const float4*)ws_)[k * Q + q];
    acc.x = fmaf(hv, wv.x, acc.x);
    acc.y = fmaf(hv, wv.y, acc.y);
    acc.z = fmaf(hv, wv.z, acc.z);
    acc.w = fmaf(hv, wv.w, acc.w);
  }
  if constexpr (DO_BN) {
    const float4 a = ((const float4*)bnA)[q];
    const float4 b = ((const float4*)bnB)[q];
    acc.x = fmaf(acc.x, a.x, b.x);
    acc.y = fmaf(acc.y, a.y, b.y);
    acc.z = fmaf(acc.z, a.z, b.z);
    acc.w = fmaf(acc.w, a.w, b.w);
  }
  acc.x = acc.x > 0.f ? acc.x : 0.f;
  acc.y = acc.y > 0.f ? acc.y : 0.f;
  acc.z = acc.z > 0.f ? acc.z : 0.f;
  acc.w = acc.w > 0.f ? acc.w : 0.f;
  if (n < N) ((float4*)out)[(size_t)n * Q + q] = acc;
}

// ---------------------------------------------------------------------------
// Global mean pool: batch is sorted, so accumulate runs in registers and
// flush one atomic per (run x feature).
// ---------------------------------------------------------------------------
__global__ __launch_bounds__(128) void pool_kernel(
    const float* __restrict__ h, const int* __restrict__ batch,
    float* __restrict__ sums, int* __restrict__ cnt, int N) {
  const int f = threadIdx.x;
  const int chunk = (N + gridDim.x - 1) / gridDim.x;
  const int n0 = blockIdx.x * chunk;
  const int n1 = min(n0 + chunk, N);
  int curg = -1;
  float acc = 0.f;
  int c = 0;
  for (int n = n0; n < n1; ++n) {
    const int g = batch[n];
    if (g != curg) {
      if (curg >= 0) {
        if (f < 96) unsafeAtomicAdd(&sums[curg * 96 + f], acc);
        if (f == 0) atomicAdd(&cnt[curg], c);
      }
      curg = g;
      acc = 0.f;
      c = 0;
    }
    if (f < 96) acc += h[(size_t)n * 96 + f];
    ++c;
  }
  if (curg >= 0) {
    if (f < 96) unsafeAtomicAdd(&sums[curg * 96 + f], acc);
    if (f == 0) atomicAdd(&cnt[curg], c);
  }
}

__global__ void finalize_kernel(const float* __restrict__ sums,
                                const int* __restrict__ cnt,
                                float* __restrict__ out) {
  const int i = blockIdx.x * blockDim.x + threadIdx.x;
  if (i < N_GRAPHS * 96) {
    const int g = i / 96;
    const float c = (float)cnt[g];
    out[i] = sums[i] / fmaxf(c, 1.f);
  }
}

// ---------------------------------------------------------------------------
extern "C" void kernel_launch(void* const* d_in, const int* in_sizes, int n_in,
                              void* d_out, int out_size, void* d_ws,
                              size_t ws_size, hipStream_t stream) {
  const int N = N_NODES;
  const int E = N_EDGES;

  const float* x = (const float*)d_in[0];
  const float* ea = (const float*)d_in[1];
  const int* ei = (const int*)d_in[2];
  const int* batch = (const int*)d_in[3];
  auto L = [&](int l, int idx) { return (const float*)d_in[4 + 10 * l + idx]; };
  // per-layer order: le_w(0) le_b(1) w1(2) b1(3) w2(4) b2(5) bng(6) bnb(7) bnm(8) bnv(9)

  float* ws = (float*)d_ws;
  float* agg = ws;                        // N*128 max
  float* hA = agg + (size_t)N * 128;      // N*96 (layer0 out, later layer2 out)
  float* hB = hA + (size_t)N * 96;        // N*64 (layer1 out)
  float* t1 = hB + (size_t)N * 64;        // N*96 (MLP hidden)
  float* sums = t1 + (size_t)N * 96;      // G*96
  int* cnt = (int*)(sums + N_GRAPHS * 96);

  const int gN8 = (N + 7) / 8;

  // ---- Layer 0: din=128, dout=64
  hipMemsetAsync(agg, 0, (size_t)N * 128 * 4, stream);
  edge_kernel<128><<<2048, 256, 0, stream>>>(x, ea, ei, L(0, 0), L(0, 1), agg, E);
  mlp_gemm<128, 64, true, false><<<gN8, 128, 0, stream>>>(
      x, agg, L(0, 2), L(0, 3), nullptr, nullptr, nullptr, nullptr, t1, N);
  mlp_gemm<64, 64, false, true><<<gN8, 128, 0, stream>>>(
      t1, nullptr, L(0, 4), L(0, 5), L(0, 6), L(0, 7), L(0, 8), L(0, 9), hA, N);

  // ---- Layer 1: din=64, dout=64
  hipMemsetAsync(agg, 0, (size_t)N * 64 * 4, stream);
  edge_kernel<64><<<2048, 256, 0, stream>>>(hA, ea, ei, L(1, 0), L(1, 1), agg, E);
  mlp_gemm<64, 64, true, false><<<gN8, 128, 0, stream>>>(
      hA, agg, L(1, 2), L(1, 3), nullptr, nullptr, nullptr, nullptr, t1, N);
  mlp_gemm<64, 64, false, true><<<gN8, 128, 0, stream>>>(
      t1, nullptr, L(1, 4), L(1, 5), L(1, 6), L(1, 7), L(1, 8), L(1, 9), hB, N);

  // ---- Layer 2: din=64, dout=96
  hipMemsetAsync(agg, 0, (size_t)N * 64 * 4, stream);
  edge_kernel<64><<<2048, 256, 0, stream>>>(hB, ea, ei, L(2, 0), L(2, 1), agg, E);
  mlp_gemm<64, 96, true, false><<<gN8, 192, 0, stream>>>(
      hB, agg, L(2, 2), L(2, 3), nullptr, nullptr, nullptr, nullptr, t1, N);
  mlp_gemm<96, 96, false, true><<<gN8, 192, 0, stream>>>(
      t1, nullptr, L(2, 4), L(2, 5), L(2, 6), L(2, 7), L(2, 8), L(2, 9), hA, N);

  // ---- Global mean pool
  hipMemsetAsync(sums, 0, (size_t)(N_GRAPHS * 96 + N_GRAPHS) * 4, stream);
  pool_kernel<<<512, 128, 0, stream>>>(hA, batch, sums, cnt, N);
  finalize_kernel<<<48, 128, 0, stream>>>(sums, cnt, (float*)d_out);
}

// Round 2
// 978.273 us; speedup vs baseline: 1.1884x; 1.1884x over previous
//
#include <hip/hip_runtime.h>
#include <hip/hip_bf16.h>

#define N_NODES 50000
#define N_EDGES 800000
#define N_GRAPHS 64

// ---------------------------------------------------------------------------
// CSR build (once per call; edge_index is shared by all 3 layers).
// ---------------------------------------------------------------------------
__global__ __launch_bounds__(256) void hist_kernel(const int* __restrict__ ei,
                                                   int* __restrict__ deg, int E) {
  int e = blockIdx.x * 256 + threadIdx.x;
  if (e < E) atomicAdd(&deg[ei[E + e]], 1);
}

__global__ __launch_bounds__(1024) void scan_kernel(const int* __restrict__ deg,
                                                    int* __restrict__ row_start,
                                                    int* __restrict__ cursor, int N) {
  __shared__ int part[1024];
  const int t = threadIdx.x;
  const int C = (N + 1023) / 1024;
  const int b0 = min(t * C, N);
  const int b1 = min(b0 + C, N);
  int s = 0;
  for (int i = b0; i < b1; ++i) s += deg[i];
  part[t] = s;
  __syncthreads();
  for (int off = 1; off < 1024; off <<= 1) {
    int v = (t >= off) ? part[t - off] : 0;
    __syncthreads();
    part[t] += v;
    __syncthreads();
  }
  int ex = (t == 0) ? 0 : part[t - 1];
  for (int i = b0; i < b1; ++i) {
    row_start[i] = ex;
    cursor[i] = ex;
    ex += deg[i];
  }
  if (t == 1023) row_start[N] = part[1023];
}

__global__ __launch_bounds__(256) void scatter_kernel(const int* __restrict__ ei,
                                                      int* __restrict__ cursor,
                                                      int2* __restrict__ epair, int E) {
  int e = blockIdx.x * 256 + threadIdx.x;
  if (e < E) {
    int d = ei[E + e];
    int p = atomicAdd(&cursor[d], 1);
    epair[p] = make_int2(e, ei[e]);  // (edge id, src node)
  }
}

// ---------------------------------------------------------------------------
// Fused GINE gather: one wave per node. Accumulate sum_e relu(x[src] + ea[e]@lew
// + leb) in registers (no atomics), then write hpre = x[n] + acc.
// lew column tile pinned in VGPRs via identity asm. ea rows are wave-uniform ->
// scalar (s_load) reads feeding v_fma with SGPR broadcast operand.
// ---------------------------------------------------------------------------
template <int DIN>
__global__ __launch_bounds__(256) void gine_gather(
    const float* __restrict__ x, const float* __restrict__ ea,
    const int* __restrict__ row_start, const int2* __restrict__ epair,
    const float* __restrict__ lew, const float* __restrict__ leb,
    float* __restrict__ hpre, int N) {
  constexpr int FPL = DIN / 64;  // features per lane
  const int lane = threadIdx.x & 63;
  const int wv = __builtin_amdgcn_readfirstlane(blockIdx.x * 4 + (threadIdx.x >> 6));
  const int nw = gridDim.x * 4;

  float w[32][FPL];
  float bb[FPL];
#pragma unroll
  for (int p = 0; p < FPL; ++p) bb[p] = leb[lane + 64 * p];
#pragma unroll
  for (int k = 0; k < 32; ++k)
#pragma unroll
    for (int p = 0; p < FPL; ++p) {
      w[k][p] = lew[k * DIN + lane + 64 * p];
      asm("" : "+v"(w[k][p]));  // pin in VGPR; forbid rematerializing the load
    }

  for (int n = wv; n < N; n += nw) {
    const int e0 = row_start[n];
    const int e1 = row_start[n + 1];
    float acc[FPL];
#pragma unroll
    for (int p = 0; p < FPL; ++p) acc[p] = 0.f;

    for (int i = e0; i < e1; ++i) {
      const int2 es = epair[i];
      const int e = __builtin_amdgcn_readfirstlane(es.x);
      const int s = __builtin_amdgcn_readfirstlane(es.y);
      const float* __restrict__ earow = ea + (size_t)e * 32;
      float t[FPL];
#pragma unroll
      for (int p = 0; p < FPL; ++p) t[p] = bb[p];
#pragma unroll
      for (int k = 0; k < 32; ++k) {
        const float eak = earow[k];  // uniform addr -> s_load, SGPR operand
#pragma unroll
        for (int p = 0; p < FPL; ++p) t[p] = fmaf(eak, w[k][p], t[p]);
      }
#pragma unroll
      for (int p = 0; p < FPL; ++p) {
        const float m = t[p] + x[(size_t)s * DIN + lane + 64 * p];
        acc[p] += fmaxf(m, 0.f);
      }
    }
#pragma unroll
    for (int p = 0; p < FPL; ++p)
      hpre[(size_t)n * DIN + lane + 64 * p] =
          x[(size_t)n * DIN + lane + 64 * p] + acc[p];
  }
}

// ---------------------------------------------------------------------------
// Node GEMM: out[n,f] = relu((in[n,:]) @ w + bias), optional eval-mode BN
// folded in before the relu. 8 nodes/block, 4 outputs/thread, w in LDS.
// ---------------------------------------------------------------------------
template <int K, int M, bool DO_BN>
__global__ void mlp_gemm(const float* __restrict__ in, const float* __restrict__ w,
                         const float* __restrict__ bias, const float* __restrict__ bng,
                         const float* __restrict__ bnb, const float* __restrict__ bnm,
                         const float* __restrict__ bnv, float* __restrict__ out, int N) {
  constexpr int Q = M / 4;  // threads per node
  constexpr int NPB = 8;    // nodes per block
  __shared__ alignas(16) float ws_[K * M];
  __shared__ alignas(16) float hin[NPB * K];
  __shared__ alignas(16) float bnA[DO_BN ? M : 4];
  __shared__ alignas(16) float bnB[DO_BN ? M : 4];

  const int tid = threadIdx.x;
  const int bdim = Q * NPB;

  for (int i = tid; i < K * M / 4; i += bdim)
    ((float4*)ws_)[i] = ((const float4*)w)[i];
  if constexpr (DO_BN) {
    for (int f = tid; f < M; f += bdim) {
      float s = bng[f] * rsqrtf(bnv[f] + 1e-5f);
      bnA[f] = s;
      bnB[f] = bnb[f] - bnm[f] * s;
    }
  }
  const int nb = blockIdx.x * NPB;
  for (int i = tid; i < NPB * K; i += bdim) {
    const int dn = i / K;
    const int col = i - dn * K;
    const int n = nb + dn;
    hin[i] = (n < N) ? in[(size_t)n * K + col] : 0.f;
  }
  __syncthreads();

  const int ns = tid / Q;
  const int q = tid - ns * Q;
  const int n = nb + ns;

  float4 acc = ((const float4*)bias)[q];
#pragma unroll 8
  for (int k = 0; k < K; ++k) {
    const float hv = hin[ns * K + k];
    const float4 wv = ((const float4*)ws_)[k * Q + q];
    acc.x = fmaf(hv, wv.x, acc.x);
    acc.y = fmaf(hv, wv.y, acc.y);
    acc.z = fmaf(hv, wv.z, acc.z);
    acc.w = fmaf(hv, wv.w, acc.w);
  }
  if constexpr (DO_BN) {
    const float4 a = ((const float4*)bnA)[q];
    const float4 b = ((const float4*)bnB)[q];
    acc.x = fmaf(acc.x, a.x, b.x);
    acc.y = fmaf(acc.y, a.y, b.y);
    acc.z = fmaf(acc.z, a.z, b.z);
    acc.w = fmaf(acc.w, a.w, b.w);
  }
  acc.x = acc.x > 0.f ? acc.x : 0.f;
  acc.y = acc.y > 0.f ? acc.y : 0.f;
  acc.z = acc.z > 0.f ? acc.z : 0.f;
  acc.w = acc.w > 0.f ? acc.w : 0.f;
  if (n < N) ((float4*)out)[(size_t)n * Q + q] = acc;
}

// ---------------------------------------------------------------------------
// Global mean pool over sorted batch ids: register run-accumulate, one atomic
// per (run x feature).
// ---------------------------------------------------------------------------
__global__ __launch_bounds__(128) void pool_kernel(const float* __restrict__ h,
                                                   const int* __restrict__ batch,
                                                   float* __restrict__ sums,
                                                   int* __restrict__ cnt, int N) {
  const int f = threadIdx.x;
  const int chunk = (N + gridDim.x - 1) / gridDim.x;
  const int n0 = blockIdx.x * chunk;
  const int n1 = min(n0 + chunk, N);
  int curg = -1;
  float acc = 0.f;
  int c = 0;
  for (int n = n0; n < n1; ++n) {
    const int g = batch[n];
    if (g != curg) {
      if (curg >= 0) {
        if (f < 96) unsafeAtomicAdd(&sums[curg * 96 + f], acc);
        if (f == 0) atomicAdd(&cnt[curg], c);
      }
      curg = g;
      acc = 0.f;
      c = 0;
    }
    if (f < 96) acc += h[(size_t)n * 96 + f];
    ++c;
  }
  if (curg >= 0) {
    if (f < 96) unsafeAtomicAdd(&sums[curg * 96 + f], acc);
    if (f == 0) atomicAdd(&cnt[curg], c);
  }
}

__global__ void finalize_kernel(const float* __restrict__ sums,
                                const int* __restrict__ cnt, float* __restrict__ out) {
  const int i = blockIdx.x * blockDim.x + threadIdx.x;
  if (i < N_GRAPHS * 96) {
    const int g = i / 96;
    const float c = (float)cnt[g];
    out[i] = sums[i] / fmaxf(c, 1.f);
  }
}

// ---------------------------------------------------------------------------
extern "C" void kernel_launch(void* const* d_in, const int* in_sizes, int n_in,
                              void* d_out, int out_size, void* d_ws, size_t ws_size,
                              hipStream_t stream) {
  const int N = N_NODES;
  const int E = N_EDGES;

  const float* x = (const float*)d_in[0];
  const float* ea = (const float*)d_in[1];
  const int* ei = (const int*)d_in[2];
  const int* batch = (const int*)d_in[3];
  auto L = [&](int l, int idx) { return (const float*)d_in[4 + 10 * l + idx]; };
  // per-layer: le_w(0) le_b(1) w1(2) b1(3) w2(4) b2(5) bng(6) bnb(7) bnm(8) bnv(9)

  // ---- workspace layout (int region first, then 16B-aligned float region)
  int* iws = (int*)d_ws;
  int* deg = iws;                       // N
  int* row_start = deg + N;             // N+1
  int* cursor = row_start + N + 1;      // N
  int2* epair = (int2*)(iws + 150004);  // E pairs (8B aligned)
  float* fws = (float*)(iws + 150004 + 2 * E);  // 16B aligned (index %4 == 0)
  float* hpre = fws;                    // N*128 (largest layer input)
  float* t1 = hpre + (size_t)N * 128;   // N*96 (MLP hidden)
  float* hA = t1 + (size_t)N * 96;      // N*96 (layer0 out / layer2 out)
  float* hB = hA + (size_t)N * 96;      // N*64 (layer1 out)
  float* sums = hB + (size_t)N * 64;    // G*96
  int* cnt = (int*)(sums + N_GRAPHS * 96);

  const int gE = (E + 255) / 256;
  const int gW = (N + 3) / 4;  // one wave per node, 4 waves/block
  const int gN8 = (N + 7) / 8;

  // ---- CSR build (edge_index shared across layers)
  hipMemsetAsync(deg, 0, (size_t)N * 4, stream);
  hist_kernel<<<gE, 256, 0, stream>>>(ei, deg, E);
  scan_kernel<<<1, 1024, 0, stream>>>(deg, row_start, cursor, N);
  scatter_kernel<<<gE, 256, 0, stream>>>(ei, cursor, epair, E);

  // ---- Layer 0: din=128 -> hid=64 -> out=64
  gine_gather<128><<<gW, 256, 0, stream>>>(x, ea, row_start, epair, L(0, 0), L(0, 1), hpre, N);
  mlp_gemm<128, 64, false><<<gN8, 128, 0, stream>>>(
      hpre, L(0, 2), L(0, 3), nullptr, nullptr, nullptr, nullptr, t1, N);
  mlp_gemm<64, 64, true><<<gN8, 128, 0, stream>>>(
      t1, L(0, 4), L(0, 5), L(0, 6), L(0, 7), L(0, 8), L(0, 9), hA, N);

  // ---- Layer 1: din=64 -> 64 -> 64
  gine_gather<64><<<gW, 256, 0, stream>>>(hA, ea, row_start, epair, L(1, 0), L(1, 1), hpre, N);
  mlp_gemm<64, 64, false><<<gN8, 128, 0, stream>>>(
      hpre, L(1, 2), L(1, 3), nullptr, nullptr, nullptr, nullptr, t1, N);
  mlp_gemm<64, 64, true><<<gN8, 128, 0, stream>>>(
      t1, L(1, 4), L(1, 5), L(1, 6), L(1, 7), L(1, 8), L(1, 9), hB, N);

  // ---- Layer 2: din=64 -> 96 -> 96
  gine_gather<64><<<gW, 256, 0, stream>>>(hB, ea, row_start, epair, L(2, 0), L(2, 1), hpre, N);
  mlp_gemm<64, 96, false><<<gN8, 192, 0, stream>>>(
      hpre, L(2, 2), L(2, 3), nullptr, nullptr, nullptr, nullptr, t1, N);
  mlp_gemm<96, 96, true><<<gN8, 192, 0, stream>>>(
      t1, L(2, 4), L(2, 5), L(2, 6), L(2, 7), L(2, 8), L(2, 9), hA, N);

  // ---- Global mean pool
  hipMemsetAsync(sums, 0, (size_t)(N_GRAPHS * 96 + N_GRAPHS) * 4, stream);
  pool_kernel<<<512, 128, 0, stream>>>(hA, batch, sums, cnt, N);
  finalize_kernel<<<48, 128, 0, stream>>>(sums, cnt, (float*)d_out);
}

// Round 3
// 974.953 us; speedup vs baseline: 1.1925x; 1.0034x over previous
//
#include <hip/hip_runtime.h>
#include <hip/hip_bf16.h>

#define N_NODES 50000
#define N_EDGES 800000
#define N_GRAPHS 64

// ---------------------------------------------------------------------------
// CSR build (once per call; edge_index is shared by all 3 layers).
// ---------------------------------------------------------------------------
__global__ __launch_bounds__(256) void hist_kernel(const int* __restrict__ ei,
                                                   int* __restrict__ deg, int E) {
  int e = blockIdx.x * 256 + threadIdx.x;
  if (e < E) atomicAdd(&deg[ei[E + e]], 1);
}

__global__ __launch_bounds__(1024) void scan_kernel(const int* __restrict__ deg,
                                                    int* __restrict__ row_start,
                                                    int* __restrict__ cursor, int N) {
  __shared__ int part[1024];
  const int t = threadIdx.x;
  const int C = (N + 1023) / 1024;
  const int b0 = min(t * C, N);
  const int b1 = min(b0 + C, N);
  int s = 0;
  for (int i = b0; i < b1; ++i) s += deg[i];
  part[t] = s;
  __syncthreads();
  for (int off = 1; off < 1024; off <<= 1) {
    int v = (t >= off) ? part[t - off] : 0;
    __syncthreads();
    part[t] += v;
    __syncthreads();
  }
  int ex = (t == 0) ? 0 : part[t - 1];
  for (int i = b0; i < b1; ++i) {
    row_start[i] = ex;
    cursor[i] = ex;
    ex += deg[i];
  }
  if (t == 1023) row_start[N] = part[1023];
}

__global__ __launch_bounds__(256) void scatter_kernel(const int* __restrict__ ei,
                                                      int* __restrict__ cursor,
                                                      int2* __restrict__ epair, int E) {
  int e = blockIdx.x * 256 + threadIdx.x;
  if (e < E) {
    int d = ei[E + e];
    int p = atomicAdd(&cursor[d], 1);
    epair[p] = make_int2(e, ei[e]);  // (edge id, src node)
  }
}

// ---------------------------------------------------------------------------
// Fused GINE gather. One wave per (node, 64-col slice). lew staged in LDS once
// per block (shared by 4 waves); inner loop batches 4 edges so each ds_read of
// a weight value feeds 4 FMAs. ea rows are wave-uniform (readfirstlane'd edge
// id) -> scalar loads; x rows are vector-gathered 256B coalesced.
// ---------------------------------------------------------------------------
template <int DIN>
__global__ __launch_bounds__(256) void gine_gather(
    const float* __restrict__ x, const float* __restrict__ ea,
    const int* __restrict__ row_start, const int2* __restrict__ epair,
    const float* __restrict__ lew, const float* __restrict__ leb,
    float* __restrict__ hpre, int N) {
  constexpr int WPN = DIN / 64;  // 64-col slices per node
  __shared__ float wlds[32 * DIN];
  const int tid = threadIdx.x;
  for (int i = tid; i < 32 * DIN / 4; i += 256)
    ((float4*)wlds)[i] = ((const float4*)lew)[i];
  __syncthreads();

  const int gw = blockIdx.x * 4 + (tid >> 6);
  if (gw >= N * WPN) return;
  const int lane = tid & 63;
  const int n = gw / WPN;
  const int off = (gw % WPN) * 64 + lane;  // feature index

  const float bb = leb[off];
  const int e0 = row_start[n];
  const int e1 = row_start[n + 1];
  float acc = 0.f;

  for (int i = e0; i < e1; i += 4) {
    int ee[4], ss[4];
    float val[4];
#pragma unroll
    for (int j = 0; j < 4; ++j) {
      const int idx = (i + j < e1) ? (i + j) : (e1 - 1);
      const int2 p = epair[idx];
      ee[j] = __builtin_amdgcn_readfirstlane(p.x);
      ss[j] = __builtin_amdgcn_readfirstlane(p.y);
      val[j] = (i + j < e1) ? 1.f : 0.f;
    }
    float xv[4], t[4];
#pragma unroll
    for (int j = 0; j < 4; ++j) {
      xv[j] = x[(size_t)ss[j] * DIN + off];
      t[j] = bb;
    }
    const float* __restrict__ r0 = ea + (size_t)ee[0] * 32;
    const float* __restrict__ r1 = ea + (size_t)ee[1] * 32;
    const float* __restrict__ r2 = ea + (size_t)ee[2] * 32;
    const float* __restrict__ r3 = ea + (size_t)ee[3] * 32;
#pragma unroll
    for (int k = 0; k < 32; ++k) {
      const float wk = wlds[k * DIN + off];  // 1 ds_read feeds 4 FMAs
      t[0] = fmaf(r0[k], wk, t[0]);
      t[1] = fmaf(r1[k], wk, t[1]);
      t[2] = fmaf(r2[k], wk, t[2]);
      t[3] = fmaf(r3[k], wk, t[3]);
    }
#pragma unroll
    for (int j = 0; j < 4; ++j) acc += val[j] * fmaxf(xv[j] + t[j], 0.f);
  }
  hpre[(size_t)n * DIN + off] = x[(size_t)n * DIN + off] + acc;
}

// ---------------------------------------------------------------------------
// Fused per-layer MLP: out = relu(BN(relu(in@w1+b1) @ w2 + b2)).
// Hidden width == M (the layer's dout). 32 nodes/block; each thread computes a
// 4-node x 4-col register tile. w2 is staged into the same LDS region as
// w1/hin after phase 1 (they're disjoint in time) to keep LDS small.
// blockDim = (M/4)*8.
// ---------------------------------------------------------------------------
template <int K, int M>
__global__ __launch_bounds__((M / 4) * 8) void mlp_fused(
    const float* __restrict__ in, const float* __restrict__ w1,
    const float* __restrict__ b1, const float* __restrict__ w2,
    const float* __restrict__ b2, const float* __restrict__ bng,
    const float* __restrict__ bnb, const float* __restrict__ bnm,
    const float* __restrict__ bnv, float* __restrict__ out, int N) {
  constexpr int NPB = 32;
  constexpr int SK = K + 4;
  constexpr int SH = M + 4;
  constexpr int Q = M / 4;
  constexpr int TH = Q * 8;
  constexpr int R1 = K * M + NPB * SK;
  constexpr int SZA = (R1 > M * M) ? R1 : (M * M);
  __shared__ alignas(16) float smem[SZA + NPB * SH + 2 * M];
  float* w1l = smem;            // phase 1
  float* hin = smem + K * M;    // phase 1
  float* w2l = smem;            // phase 2 (overlaps w1l/hin)
  float* h1 = smem + SZA;
  float* bnA = h1 + NPB * SH;
  float* bnB = bnA + M;

  const int tid = threadIdx.x;
  const int nb = blockIdx.x * NPB;

  for (int i = tid; i < K * M / 4; i += TH)
    ((float4*)w1l)[i] = ((const float4*)w1)[i];
  for (int f = tid; f < M; f += TH) {
    const float s = bng[f] * rsqrtf(bnv[f] + 1e-5f);
    bnA[f] = s;
    bnB[f] = bnb[f] - bnm[f] * s;
  }
  for (int i = tid; i < NPB * (K / 4); i += TH) {
    const int dn = i / (K / 4);
    const int kq = i % (K / 4);
    const int n = nb + dn;
    float4 v = make_float4(0.f, 0.f, 0.f, 0.f);
    if (n < N) v = ((const float4*)(in + (size_t)n * K))[kq];
    ((float4*)(hin + dn * SK))[kq] = v;
  }
  __syncthreads();

  const int q = tid % Q;
  const int ng = tid / Q;

  // ---- phase 1: h1 = relu(in @ w1 + b1)
  {
    const float4 bias = ((const float4*)b1)[q];
    float4 a[4] = {bias, bias, bias, bias};
#pragma unroll 4
    for (int k = 0; k < K; ++k) {
      const float4 wv = ((const float4*)w1l)[k * Q + q];
#pragma unroll
      for (int r = 0; r < 4; ++r) {
        const float hv = hin[(ng * 4 + r) * SK + k];
        a[r].x = fmaf(hv, wv.x, a[r].x);
        a[r].y = fmaf(hv, wv.y, a[r].y);
        a[r].z = fmaf(hv, wv.z, a[r].z);
        a[r].w = fmaf(hv, wv.w, a[r].w);
      }
    }
    __syncthreads();  // everyone done reading w1l/hin before h1... (h1 disjoint) -- ordering for w2l overwrite
#pragma unroll
    for (int r = 0; r < 4; ++r) {
      float4 v = a[r];
      v.x = fmaxf(v.x, 0.f);
      v.y = fmaxf(v.y, 0.f);
      v.z = fmaxf(v.z, 0.f);
      v.w = fmaxf(v.w, 0.f);
      ((float4*)(h1 + (ng * 4 + r) * SH))[q] = v;
    }
  }
  // ---- stage w2 into the (now free) region
  for (int i = tid; i < M * M / 4; i += TH)
    ((float4*)w2l)[i] = ((const float4*)w2)[i];
  __syncthreads();

  // ---- phase 2: out = relu(BN(h1 @ w2 + b2))
  {
    const float4 bias = ((const float4*)b2)[q];
    float4 a[4] = {bias, bias, bias, bias};
#pragma unroll 4
    for (int k = 0; k < M; ++k) {
      const float4 wv = ((const float4*)w2l)[k * Q + q];
#pragma unroll
      for (int r = 0; r < 4; ++r) {
        const float hv = h1[(ng * 4 + r) * SH + k];
        a[r].x = fmaf(hv, wv.x, a[r].x);
        a[r].y = fmaf(hv, wv.y, a[r].y);
        a[r].z = fmaf(hv, wv.z, a[r].z);
        a[r].w = fmaf(hv, wv.w, a[r].w);
      }
    }
    const float4 A = ((const float4*)bnA)[q];
    const float4 B = ((const float4*)bnB)[q];
#pragma unroll
    for (int r = 0; r < 4; ++r) {
      const int n = nb + ng * 4 + r;
      if (n < N) {
        float4 v = a[r];
        v.x = fmaxf(fmaf(v.x, A.x, B.x), 0.f);
        v.y = fmaxf(fmaf(v.y, A.y, B.y), 0.f);
        v.z = fmaxf(fmaf(v.z, A.z, B.z), 0.f);
        v.w = fmaxf(fmaf(v.w, A.w, B.w), 0.f);
        ((float4*)(out + (size_t)n * M))[q] = v;
      }
    }
  }
}

// ---------------------------------------------------------------------------
// Global mean pool over sorted batch ids.
// ---------------------------------------------------------------------------
__global__ __launch_bounds__(128) void pool_kernel(const float* __restrict__ h,
                                                   const int* __restrict__ batch,
                                                   float* __restrict__ sums,
                                                   int* __restrict__ cnt, int N) {
  const int f = threadIdx.x;
  const int chunk = (N + gridDim.x - 1) / gridDim.x;
  const int n0 = blockIdx.x * chunk;
  const int n1 = min(n0 + chunk, N);
  int curg = -1;
  float acc = 0.f;
  int c = 0;
  for (int n = n0; n < n1; ++n) {
    const int g = batch[n];
    if (g != curg) {
      if (curg >= 0) {
        if (f < 96) unsafeAtomicAdd(&sums[curg * 96 + f], acc);
        if (f == 0) atomicAdd(&cnt[curg], c);
      }
      curg = g;
      acc = 0.f;
      c = 0;
    }
    if (f < 96) acc += h[(size_t)n * 96 + f];
    ++c;
  }
  if (curg >= 0) {
    if (f < 96) unsafeAtomicAdd(&sums[curg * 96 + f], acc);
    if (f == 0) atomicAdd(&cnt[curg], c);
  }
}

__global__ void finalize_kernel(const float* __restrict__ sums,
                                const int* __restrict__ cnt, float* __restrict__ out) {
  const int i = blockIdx.x * blockDim.x + threadIdx.x;
  if (i < N_GRAPHS * 96) {
    const int g = i / 96;
    const float c = (float)cnt[g];
    out[i] = sums[i] / fmaxf(c, 1.f);
  }
}

// ---------------------------------------------------------------------------
extern "C" void kernel_launch(void* const* d_in, const int* in_sizes, int n_in,
                              void* d_out, int out_size, void* d_ws, size_t ws_size,
                              hipStream_t stream) {
  const int N = N_NODES;
  const int E = N_EDGES;

  const float* x = (const float*)d_in[0];
  const float* ea = (const float*)d_in[1];
  const int* ei = (const int*)d_in[2];
  const int* batch = (const int*)d_in[3];
  auto L = [&](int l, int idx) { return (const float*)d_in[4 + 10 * l + idx]; };
  // per-layer: le_w(0) le_b(1) w1(2) b1(3) w2(4) b2(5) bng(6) bnb(7) bnm(8) bnv(9)

  // ---- workspace layout
  int* iws = (int*)d_ws;
  int* deg = iws;                       // N
  int* row_start = deg + N;             // N+1
  int* cursor = row_start + N + 1;      // N
  int2* epair = (int2*)(iws + 150004);  // E pairs
  float* fws = (float*)(iws + 150004 + 2 * E);  // 16B aligned
  float* hpre = fws;                    // N*128 max
  float* hA = hpre + (size_t)N * 128;   // N*96
  float* hB = hA + (size_t)N * 96;      // N*64
  float* sums = hB + (size_t)N * 64;    // G*96
  int* cnt = (int*)(sums + N_GRAPHS * 96);

  const int gE = (E + 255) / 256;
  const int gN32 = (N + 31) / 32;

  // ---- CSR build
  hipMemsetAsync(deg, 0, (size_t)N * 4, stream);
  hist_kernel<<<gE, 256, 0, stream>>>(ei, deg, E);
  scan_kernel<<<1, 1024, 0, stream>>>(deg, row_start, cursor, N);
  scatter_kernel<<<gE, 256, 0, stream>>>(ei, cursor, epair, E);

  // ---- Layer 0: din=128 -> 64
  gine_gather<128><<<(N * 2 + 3) / 4, 256, 0, stream>>>(
      x, ea, row_start, epair, L(0, 0), L(0, 1), hpre, N);
  mlp_fused<128, 64><<<gN32, 128, 0, stream>>>(
      hpre, L(0, 2), L(0, 3), L(0, 4), L(0, 5), L(0, 6), L(0, 7), L(0, 8), L(0, 9), hA, N);

  // ---- Layer 1: din=64 -> 64
  gine_gather<64><<<(N + 3) / 4, 256, 0, stream>>>(
      hA, ea, row_start, epair, L(1, 0), L(1, 1), hpre, N);
  mlp_fused<64, 64><<<gN32, 128, 0, stream>>>(
      hpre, L(1, 2), L(1, 3), L(1, 4), L(1, 5), L(1, 6), L(1, 7), L(1, 8), L(1, 9), hB, N);

  // ---- Layer 2: din=64 -> 96
  gine_gather<64><<<(N + 3) / 4, 256, 0, stream>>>(
      hB, ea, row_start, epair, L(2, 0), L(2, 1), hpre, N);
  mlp_fused<64, 96><<<gN32, 192, 0, stream>>>(
      hpre, L(2, 2), L(2, 3), L(2, 4), L(2, 5), L(2, 6), L(2, 7), L(2, 8), L(2, 9), hA, N);

  // ---- Global mean pool
  hipMemsetAsync(sums, 0, (size_t)(N_GRAPHS * 96 + N_GRAPHS) * 4, stream);
  pool_kernel<<<512, 128, 0, stream>>>(hA, batch, sums, cnt, N);
  finalize_kernel<<<48, 128, 0, stream>>>(sums, cnt, (float*)d_out);
}